// Round 1
// baseline (693.205 us; speedup 1.0000x reference)
//
#include <hip/hip_runtime.h>
#include <hip/hip_bf16.h>

typedef __attribute__((ext_vector_type(8))) short short8;
typedef __attribute__((ext_vector_type(4))) float f32x4;

#define HID     512
#define OUTD    256
#define ROWS    32
#define THREADS 512
#define NKT     16          // K/32
#define KT_SPLIT 13         // kt >= 13 served from LDS cache (3 kt * 32 ntg * 1KB = 96KB)

static __device__ __forceinline__ unsigned short f2bf(float x) {
    __hip_bfloat16 h = __float2bfloat16(x);
    return __builtin_bit_cast(unsigned short, h);
}
static __device__ __forceinline__ unsigned pk2(float a, float b) {
    return (unsigned)f2bf(a) | ((unsigned)f2bf(b) << 16);
}
static __device__ __forceinline__ float bflo(unsigned u) {
    unsigned v = u << 16; return __builtin_bit_cast(float, v);
}
static __device__ __forceinline__ float bfhi(unsigned u) {
    unsigned v = u & 0xffff0000u; return __builtin_bit_cast(float, v);
}
static __device__ __forceinline__ float fast_tanh(float x) {
    // tanh(x) = 1 - 2/(exp2(x*2*log2e)+1); saturates correctly for |x| large
    float e = __builtin_amdgcn_exp2f(x * 2.885390081777927f);
    float r = __builtin_amdgcn_rcpf(e + 1.0f);
    return fmaf(-2.0f, r, 1.0f);
}

// Pack row-major [N][512] f32 into MFMA-B fragment order (bf16):
// frag f = (ntg*16 + kt)*64 + lane holds M[ntg*16 + (lane&15)][kt*32 + (lane>>4)*8 + e], e=0..7
__global__ __launch_bounds__(256) void pack_weights(
    const float* __restrict__ wh, const float* __restrict__ wx,
    const float* __restrict__ hd,
    unsigned short* __restrict__ whp, unsigned short* __restrict__ wxp,
    unsigned short* __restrict__ hdp)
{
    int gid = blockIdx.x * 256 + threadIdx.x;          // [0, 81920)
    const float* src; unsigned short* dst; int f;
    if (gid < 32768)      { src = wh; dst = whp; f = gid; }
    else if (gid < 65536) { src = wx; dst = wxp; f = gid - 32768; }
    else                  { src = hd; dst = hdp; f = gid - 65536; }
    int lane = f & 63;
    int kt   = (f >> 6) & 15;
    int ntg  = f >> 10;
    int n = ntg * 16 + (lane & 15);
    int k = kt * 32 + (lane >> 4) * 8;
    const float* sp = src + (size_t)n * HID + k;
    float4 a = *(const float4*)sp;
    float4 b = *(const float4*)(sp + 4);
    uint4 o;
    o.x = pk2(a.x, a.y); o.y = pk2(a.z, a.w);
    o.z = pk2(b.x, b.y); o.w = pk2(b.z, b.w);
    *(uint4*)(dst + (size_t)f * 8) = o;
}

// 32-row A (fragment-packed in LDS) times NT 16-col tiles per wave, K=512.
// CACHED: kt >= KT_SPLIT read from LDS bc instead of global bg.
template<int NT, bool CACHED>
static __device__ __forceinline__ void gemm_tiles(
    const unsigned short* sfr, const unsigned short* __restrict__ bg,
    const unsigned short* bc, f32x4 (&acc)[2][NT], int w, int l)
{
    const int ntg0 = w * NT;
    #pragma unroll
    for (int kt = 0; kt < NKT; ++kt) {
        short8 a0 = *(const short8*)(sfr + (kt * 64 + l) * 8);
        short8 a1 = *(const short8*)(sfr + ((NKT + kt) * 64 + l) * 8);
        #pragma unroll
        for (int nt = 0; nt < NT; ++nt) {
            short8 b;
            if (CACHED && kt >= KT_SPLIT)
                b = *(const short8*)(bc + (((ntg0 + nt) * 3 + (kt - KT_SPLIT)) * 64 + l) * 8);
            else
                b = *(const short8*)(bg + (((ntg0 + nt) * NKT + kt) * 64 + l) * 8);
            acc[0][nt] = __builtin_amdgcn_mfma_f32_16x16x32_bf16(a0, b, acc[0][nt], 0, 0, 0);
            acc[1][nt] = __builtin_amdgcn_mfma_f32_16x16x32_bf16(a1, b, acc[1][nt], 0, 0, 0);
        }
    }
}

__global__ __launch_bounds__(THREADS, 2) void toroidal(
    const float* __restrict__ x,
    const unsigned short* __restrict__ wxp,
    const unsigned short* __restrict__ whp,
    const unsigned short* __restrict__ hdp,
    const float* __restrict__ wxb, const float* __restrict__ whb,
    const float* __restrict__ hdb,
    const float* __restrict__ gamma_p, const float* __restrict__ alphas,
    const int* __restrict__ steps_p,
    float* __restrict__ out)
{
    __shared__ __align__(16) unsigned short sfrag[ROWS * HID];      // 32 KiB, A-frag packed
    __shared__ __align__(16) unsigned short bc[32 * 3 * 64 * 8];    // 96 KiB, Wh kt 13..15

    const int tid = threadIdx.x;
    const int w = tid >> 6;          // wave 0..7 -> cols [w*64, w*64+64)
    const int l = tid & 63;
    const int q = l >> 4;            // 0..3 (C-frag row group)
    const int c = l & 15;            // C-frag col
    const int rbase = blockIdx.x * ROWS;

    // ---- one-time: fill LDS Wh cache (kt 13..15, all 32 ntg) ----
    #pragma unroll
    for (int j = 0; j < 12; ++j) {
        int bidx = tid + j * THREADS;              // [0, 6144)
        int ntg = bidx / 192;
        int r   = bidx - ntg * 192;
        int kt  = KT_SPLIT + (r >> 6);
        int ln  = r & 63;
        uint4 v = *(const uint4*)(whp + (size_t)((ntg * NKT + kt) * 64 + ln) * 8);
        *(uint4*)(bc + (size_t)bidx * 8) = v;
    }

    // ---- one-time: pack x tile (32 rows) into sfrag as bf16 A-fragments ----
    #pragma unroll
    for (int j = 0; j < 4; ++j) {
        int f = tid + j * THREADS;                 // [0, 2048)
        int mt = f >> 10;
        int kt = (f >> 6) & 15;
        int lf = f & 63;
        int row = mt * 16 + (lf & 15);
        int k0  = kt * 32 + (lf >> 4) * 8;
        const float* sp = x + (size_t)(rbase + row) * HID + k0;
        float4 a = *(const float4*)sp;
        float4 b = *(const float4*)(sp + 4);
        uint4 o;
        o.x = pk2(a.x, a.y); o.y = pk2(a.z, a.w);
        o.z = pk2(b.x, b.y); o.w = pk2(b.z, b.w);
        *(uint4*)(sfrag + (size_t)f * 8) = o;
    }
    __syncthreads();

    // ---- xproj = x @ Wx^T + Wx_b + Wh_b (biases folded once) ----
    f32x4 acc[2][4];
    #pragma unroll
    for (int mt = 0; mt < 2; ++mt)
        #pragma unroll
        for (int nt = 0; nt < 4; ++nt)
            acc[mt][nt] = (f32x4){0.f, 0.f, 0.f, 0.f};
    gemm_tiles<4, false>(sfrag, wxp, nullptr, acc, w, l);
    __syncthreads();   // sfrag reads done; safe to overwrite in step loop

    float xp[2][4][4];
    #pragma unroll
    for (int nt = 0; nt < 4; ++nt) {
        int col = w * 64 + nt * 16 + c;
        float bsum = wxb[col] + whb[col];
        #pragma unroll
        for (int mt = 0; mt < 2; ++mt)
            #pragma unroll
            for (int i = 0; i < 4; ++i)
                xp[mt][nt][i] = acc[mt][nt][i] + bsum;
    }

    const float g  = gamma_p[0];
    const float g1 = g * alphas[0], g2 = g * alphas[1], g3 = g * alphas[2];
    const int nsteps = steps_p[0];

    // state: s fp32 in regs; history (s_{t-1..t-3}) bf16-pair packed
    float s[2][4][4];
    unsigned hh[3][2][4][2];
    #pragma unroll
    for (int mt = 0; mt < 2; ++mt)
        #pragma unroll
        for (int nt = 0; nt < 4; ++nt)
            #pragma unroll
            for (int i = 0; i < 4; ++i) s[mt][nt][i] = 0.f;
    #pragma unroll
    for (int a = 0; a < 3; ++a)
        #pragma unroll
        for (int mt = 0; mt < 2; ++mt)
            #pragma unroll
            for (int nt = 0; nt < 4; ++nt)
                #pragma unroll
                for (int p = 0; p < 2; ++p) hh[a][mt][nt][p] = 0u;

    // per-thread base for scattering C-layout elements into A-frag-packed sfrag
    // elem (mt,nt,i): byte = mt*16384 + (nt>>1)*1024 + ((2nt)&3)*256 + i*16  +  tbase
    const int tIdx = (w * 2048 + q * 64 + (l & 7) * 2 + (((l >> 3) & 1) << 8)) >> 1;

    for (int t = 0; t < nsteps; ++t) {
        // write s (bf16) into sfrag; immediate-offset ds_write_b16 per element
        #pragma unroll
        for (int mt = 0; mt < 2; ++mt)
            #pragma unroll
            for (int nt = 0; nt < 4; ++nt)
                #pragma unroll
                for (int i = 0; i < 4; ++i) {
                    const int off = (mt * 16384 + (nt >> 1) * 1024 + ((2 * nt) & 3) * 256 + i * 16) >> 1;
                    sfrag[tIdx + off] = f2bf(s[mt][nt][i]);
                }
        __syncthreads();

        #pragma unroll
        for (int mt = 0; mt < 2; ++mt)
            #pragma unroll
            for (int nt = 0; nt < 4; ++nt)
                acc[mt][nt] = (f32x4){0.f, 0.f, 0.f, 0.f};
        gemm_tiles<4, true>(sfrag, whp, bc, acc, w, l);
        __syncthreads();   // all reads of sfrag done before next-iter overwrite

        // elementwise: pre = acc + xp + g·(a1 s-1 + a2 s-2 + a3 s-3); s = .5 s + .5 tanh(pre)
        #pragma unroll
        for (int mt = 0; mt < 2; ++mt)
            #pragma unroll
            for (int nt = 0; nt < 4; ++nt)
                #pragma unroll
                for (int p = 0; p < 2; ++p) {
                    unsigned u1 = hh[0][mt][nt][p];
                    unsigned u2 = hh[1][mt][nt][p];
                    unsigned u3 = hh[2][mt][nt][p];
                    float so0, so1;
                    {
                        const int i = p * 2;
                        float pre = acc[mt][nt][i] + xp[mt][nt][i]
                                  + g1 * bflo(u1) + g2 * bflo(u2) + g3 * bflo(u3);
                        float hn = fast_tanh(pre);
                        so0 = s[mt][nt][i];
                        s[mt][nt][i] = 0.5f * so0 + 0.5f * hn;
                    }
                    {
                        const int i = p * 2 + 1;
                        float pre = acc[mt][nt][i] + xp[mt][nt][i]
                                  + g1 * bfhi(u1) + g2 * bfhi(u2) + g3 * bfhi(u3);
                        float hn = fast_tanh(pre);
                        so1 = s[mt][nt][i];
                        s[mt][nt][i] = 0.5f * so1 + 0.5f * hn;
                    }
                    hh[2][mt][nt][p] = u2;       // shift history (old s values)
                    hh[1][mt][nt][p] = u1;
                    hh[0][mt][nt][p] = pk2(so0, so1);
                }
    }

    // ---- head: out = s_final @ Head^T + Head_b ----
    #pragma unroll
    for (int mt = 0; mt < 2; ++mt)
        #pragma unroll
        for (int nt = 0; nt < 4; ++nt)
            #pragma unroll
            for (int i = 0; i < 4; ++i) {
                const int off = (mt * 16384 + (nt >> 1) * 1024 + ((2 * nt) & 3) * 256 + i * 16) >> 1;
                sfrag[tIdx + off] = f2bf(s[mt][nt][i]);
            }
    __syncthreads();

    f32x4 acch[2][2];
    #pragma unroll
    for (int mt = 0; mt < 2; ++mt)
        #pragma unroll
        for (int nt = 0; nt < 2; ++nt)
            acch[mt][nt] = (f32x4){0.f, 0.f, 0.f, 0.f};
    gemm_tiles<2, false>(sfrag, hdp, nullptr, acch, w, l);

    #pragma unroll
    for (int nt = 0; nt < 2; ++nt) {
        int col = w * 32 + nt * 16 + c;            // 8 waves * 32 = 256 cols
        float hb = hdb[col];
        #pragma unroll
        for (int mt = 0; mt < 2; ++mt)
            #pragma unroll
            for (int i = 0; i < 4; ++i)
                out[(size_t)(rbase + mt * 16 + q * 4 + i) * OUTD + col] = acch[mt][nt][i] + hb;
    }
}

extern "C" void kernel_launch(void* const* d_in, const int* in_sizes, int n_in,
                              void* d_out, int out_size, void* d_ws, size_t ws_size,
                              hipStream_t stream) {
    (void)n_in; (void)out_size;
    const float* x    = (const float*)d_in[0];
    const float* Wx_w = (const float*)d_in[1];
    const float* Wx_b = (const float*)d_in[2];
    const float* Wh_w = (const float*)d_in[3];
    const float* Wh_b = (const float*)d_in[4];
    const float* Hd_w = (const float*)d_in[5];
    const float* Hd_b = (const float*)d_in[6];
    const float* gma  = (const float*)d_in[7];
    const float* alp  = (const float*)d_in[8];
    const int*   stp  = (const int*)d_in[9];
    float* out = (float*)d_out;

    // workspace: bf16 fragment-packed weights (512KB + 512KB + 256KB)
    if (ws_size < (size_t)(512 * 512 * 2 * 2 + 256 * 512 * 2)) return;
    unsigned short* whp = (unsigned short*)d_ws;
    unsigned short* wxp = whp + 512 * 512;
    unsigned short* hdp = wxp + 512 * 512;

    pack_weights<<<320, 256, 0, stream>>>(Wh_w, Wx_w, Hd_w, whp, wxp, hdp);

    int batch = in_sizes[0] / HID;                 // 8192
    int nblk  = batch / ROWS;                      // 256
    toroidal<<<nblk, THREADS, 0, stream>>>(x, wxp, whp, hdp, Wx_b, Wh_b, Hd_b,
                                           gma, alp, stp, out);
}